// Round 10
// baseline (111.303 us; speedup 1.0000x reference)
//
#include <hip/hip_runtime.h>
#include <hip/hip_bf16.h>
#include <math.h>
#include <stdint.h>

#define NB 4
#define NQ 100
#define NQR 101                   // partial rows: 100 queries + ones-row (Stm)
#define NCLS 81
#define NT 20
#define NHW 65536

#define SC 256                    // split-K chunks: one 256-px output row each
#define CPX (NHW / SC)            // 256 px per block

typedef __attribute__((ext_vector_type(8))) short bf16x8;
typedef __attribute__((ext_vector_type(16))) float f32x16;

__device__ inline short to_bf16(float f) {
    __hip_bfloat16 h = __float2bfloat16(f);   // RNE; pairs fuse to v_cvt_pk_bf16_f32
    return __builtin_bit_cast(short, h);
}

// v_exp_f32 / v_log_f32 are base-2 on gfx950
__device__ inline float fast_exp2(float x) { return __builtin_amdgcn_exp2f(x); }
__device__ inline float fast_log2(float x) { return __builtin_amdgcn_logf(x); }

// ---------------------------------------------------------------------------
// Kernel 1: fused main pass. One block per (b, output row h = chunk).
//  phase A: threads 0..127 gather tgt (nearest 2x downsample) -> 20-bit words
//  phase C: 4 sub-tiles of 64 px. Per sub-tile:
//    - build B-frags for 4 k-steps (bf16 0/1; col 20 = all-ones -> Ssig free)
//    - stage pm[128 rows][64 px] fp32 into LDS with COALESCED loads
//      (16 thr x 16B = 256B contiguous per row) and XOR-swizzled 16B chunks
//      (chunk ^ (row&7)) so fragment ds_reads are bank-balanced. Swizzle is
//      storage-only (applied on write AND read) -> pixel<->k map row-invariant.
//    - 4 k-steps: 2 ds_read_b128/lane + sigmoid/softplus VALU + 2 MFMAs
//      (x-GEMM -> A, sig-GEMM -> D). Padded query row 100 carries an all-ones
//      A-fragment -> A[100][t] = per-chunk popcount(tm_t) = Stm (exact fp32).
// ---------------------------------------------------------------------------
__global__ void __launch_bounds__(256)
k_main(const float* __restrict__ pm, const float* __restrict__ tgt,
       float* __restrict__ A_part, float* __restrict__ D_part,
       float* __restrict__ Sp_part) {
    int gid = blockIdx.x;
    int chunk = gid & (SC - 1);           // == output row h
    int b = gid >> 8;
    int tid = threadIdx.x;
    int wv = tid >> 6, lane = tid & 63;
    int p0 = chunk * CPX;

    __shared__ uint32_t s_tb[CPX];        // 1 KB tbits
    __shared__ float s_pm[128 * 64];      // 32 KB staged pm sub-tile (swizzled)
    __shared__ short s_bf[4][512];        // 4 KB B-frags (current sub-tile)

    // ---- phase A: gather + tbits ----
    if (tid < 128) {
        // thread i covers dst pixels (p0+2i, p0+2i+1); src row 2h, cols 4i..4i+3
        const float* base = tgt + (((size_t)b * NT) * 512 + 2 * chunk) * 512 + 4 * tid;
        uint32_t w0 = 0, w1 = 0;
#pragma unroll
        for (int t = 0; t < NT; ++t) {
            float4 v = *reinterpret_cast<const float4*>(base + (size_t)t * 512 * 512);
            w0 |= (v.x > 0.5f ? 1u : 0u) << t;
            w1 |= (v.z > 0.5f ? 1u : 0u) << t;
        }
        s_tb[2 * tid] = w0;
        s_tb[2 * tid + 1] = w1;
    }
    __syncthreads();

    int r0 = tid >> 4, cw = tid & 15;     // staging: row base, 16B-chunk index
    int Rg = wv * 32 + (lane & 31);       // this lane's query row (0..127)
    int h = lane >> 5;
    const bool ones_row = (Rg == NQ);     // row 100: A-frag = all ones -> Stm
    bf16x8 ones;
#pragma unroll
    for (int e = 0; e < 8; ++e) ones[e] = (short)0x3F80;

    f32x16 accA, accD;
#pragma unroll
    for (int r = 0; r < 16; ++r) { accA[r] = 0.0f; accD[r] = 0.0f; }
    float mxsum = 0.0f, l2sum = 0.0f;
    const float LOG2E = 1.4426950408889634f;

    for (int st = 0; st < 4; ++st) {
        // ---- B-frags for k-steps st*4..st*4+3 (one item per thread) ----
        {
            int ls = wv;                  // k-step slot this thread fills
            int col = lane & 31;
            int kbase = st * 64 + ls * 16 + (h << 3);
            uint32_t pk[4];
#pragma unroll
            for (int e2 = 0; e2 < 4; ++e2) {
                uint32_t w0 = s_tb[kbase + 2 * e2];
                uint32_t w1 = s_tb[kbase + 2 * e2 + 1];
                uint32_t lo, hi;
                if (col < NT)       { lo = ((w0 >> col) & 1u) ? 0x3F80u : 0u;
                                      hi = ((w1 >> col) & 1u) ? 0x3F80u : 0u; }
                else if (col == NT) { lo = 0x3F80u; hi = 0x3F80u; }   // ones col
                else                { lo = 0u; hi = 0u; }
                pk[e2] = lo | (hi << 16);
            }
            *reinterpret_cast<uint4*>(&s_bf[ls][lane * 8]) =
                *reinterpret_cast<const uint4*>(pk);
        }
        // ---- stage pm sub-tile (coalesced; 8 independent loads in flight) ----
#pragma unroll
        for (int p = 0; p < 8; ++p) {
            int row = r0 + 16 * p;
            int srow = (row < NQ) ? row : 0;   // pad rows read row 0 (discarded)
            float4 v = *reinterpret_cast<const float4*>(
                pm + ((size_t)(b * NQ + srow)) * NHW + (p0 + st * 64 + cw * 4));
            *reinterpret_cast<float4*>(
                &s_pm[row * 64 + ((cw ^ (row & 7)) << 2)]) = v;
        }
        __syncthreads();
        // ---- compute 4 k-steps ----
#pragma unroll
        for (int sl = 0; sl < 4; ++sl) {
            int c0 = sl * 4 + h * 2;
            float4 xa = *reinterpret_cast<const float4*>(
                &s_pm[Rg * 64 + ((c0 ^ (Rg & 7)) << 2)]);
            float4 xb4 = *reinterpret_cast<const float4*>(
                &s_pm[Rg * 64 + (((c0 + 1) ^ (Rg & 7)) << 2)]);
            float xs[8] = {xa.x, xa.y, xa.z, xa.w, xb4.x, xb4.y, xb4.z, xb4.w};
            bf16x8 af, sf;
#pragma unroll
            for (int e = 0; e < 8; ++e) {
                float xi = xs[e];
                float y = xi * LOG2E;
                float e1 = fast_exp2(0.0f - fabsf(y));  // exp(-|x|)
                float tt = 1.0f + e1;
                float inv = __builtin_amdgcn_rcpf(tt);
                float sig = (xi >= 0.0f) ? inv : e1 * inv;
                l2sum += fast_log2(tt);                 // softplus=max(x,0)+ln2*log2
                mxsum += fmaxf(xi, 0.0f);
                af[e] = to_bf16(xi);
                sf[e] = to_bf16(sig);
            }
            if (ones_row) af = ones;
            bf16x8 bf = *reinterpret_cast<const bf16x8*>(&s_bf[sl][lane * 8]);
            accA = __builtin_amdgcn_mfma_f32_32x32x16_bf16(af, bf, accA, 0, 0, 0);
            accD = __builtin_amdgcn_mfma_f32_32x32x16_bf16(sf, bf, accD, 0, 0, 0);
        }
        __syncthreads();
    }

    // Epilogue: C/D layout (verified): col = lane&31, row = (r&3)+8*(r>>2)+4*(lane>>5)
    int t = lane & 31;
#pragma unroll
    for (int r = 0; r < 16; ++r) {
        int rowD = (r & 3) + 8 * (r >> 2) + 4 * (lane >> 5);
        int qo = wv * 32 + rowD;
        if (qo <= NQ && t <= NT) {      // qo==100 is the ones/Stm row
            size_t base = ((size_t)(chunk * NB + b) * NQR + qo) * (NT + 1) + t;
            A_part[base] = accA[r];
            D_part[base] = accD[r];
        }
    }
    float sp = fmaf(0.6931471805599453f, l2sum, mxsum);
    sp += __shfl_xor(sp, 32);
    if (lane < 32 && Rg < NQ)
        Sp_part[(size_t)(chunk * NB + b) * NQ + Rg] = sp;
}

// ---------------------------------------------------------------------------
// Kernel 2: assemble C[b,q,t]. One block (256 threads) per (b,q);
// wave w reduces chunks [w*64, w*64+64) (incl. Stm row 100), LDS-combine,
// wave 0 does softmax + epilogue.
// ---------------------------------------------------------------------------
__global__ void __launch_bounds__(256)
k_assemble(const float* __restrict__ logits, const int* __restrict__ labels,
           const float* __restrict__ A_part, const float* __restrict__ D_part,
           const float* __restrict__ Sp_part, float* __restrict__ Cout) {
    constexpr int CPW = SC / 4;        // 64 chunks per wave
    int bq = blockIdx.x;
    int q = bq % NQ, b = bq / NQ;
    int tid = threadIdx.x, wv = tid >> 6, lane = tid & 63;
    __shared__ float sA[4][64], sD[4][64], sS[4][64], sSn[4];

    float At = 0.0f, Dt = 0.0f, St = 0.0f;
    int t = lane;
    for (int cc = 0; cc < CPW; ++cc) {
        int c = wv * CPW + cc;
        size_t cb = (size_t)(c * NB + b) * NQR;
        if (t <= NT) {
            At += A_part[(cb + q) * (NT + 1) + t];
            Dt += D_part[(cb + q) * (NT + 1) + t];
            St += A_part[(cb + NQ) * (NT + 1) + t];   // ones-row -> Stm
        }
    }
    {   // Sneg: lane-parallel over this wave's chunks
        int c = wv * CPW + lane;
        float sp = Sp_part[(size_t)(c * NB + b) * NQ + q];
        for (int o = 32; o; o >>= 1) sp += __shfl_xor(sp, o);
        if (lane == 0) sSn[wv] = sp;
    }
    sA[wv][lane] = At;
    sD[wv][lane] = Dt;
    sS[wv][lane] = St;
    __syncthreads();

    if (wv == 0) {
        float At4 = sA[0][lane] + sA[1][lane] + sA[2][lane] + sA[3][lane];
        float Dt4 = sD[0][lane] + sD[1][lane] + sD[2][lane] + sD[3][lane];
        float St4 = sS[0][lane] + sS[1][lane] + sS[2][lane] + sS[3][lane];
        float Sneg = sSn[0] + sSn[1] + sSn[2] + sSn[3];
        float Ssig = __shfl(Dt4, NT);                 // ones-column of D-GEMM

        const float* lg = logits + (size_t)bq * NCLS;
        float x0 = (lane < NCLS) ? lg[lane] : -INFINITY;
        float x1 = (lane + 64 < NCLS) ? lg[lane + 64] : -INFINITY;
        float mx = fmaxf(x0, x1);
        for (int o = 32; o; o >>= 1) mx = fmaxf(mx, __shfl_xor(mx, o));
        float s0 = (lane < NCLS) ? __expf(x0 - mx) : 0.0f;
        float s1 = (lane + 64 < NCLS) ? __expf(x1 - mx) : 0.0f;
        float sum = s0 + s1;
        for (int o = 32; o; o >>= 1) sum += __shfl_xor(sum, o);

        if (lane < NT) {
            int label = labels[b * NT + lane];
            float prob = __expf(lg[label] - mx) / sum;
            float cm = (Sneg - At4) * (1.0f / (float)NHW);
            float cd = 1.0f - (2.0f * Dt4 + 1.0f) / (Ssig + St4 + 1.0f);
            float c = 2.0f * (-prob) + 5.0f * cm + 5.0f * cd;
            if (isnan(c)) c = 0.0f;
            Cout[(size_t)bq * NT + lane] = c;
        }
    }
}

// ---------------------------------------------------------------------------
// Kernel 3: linear sum assignment (scipy shortest augmenting path, float64),
// on C[b].T (rows = targets 20, cols = queries 100). One wave per batch.
// ---------------------------------------------------------------------------
__global__ void __launch_bounds__(64)
k_lsa(const float* __restrict__ Cmat, float* __restrict__ out) {
    int b = blockIdx.x;
    int lane = threadIdx.x;
    __shared__ double cost[NT][NQ];
    __shared__ double u[NT], v[NQ], shortest[NQ];
    __shared__ int path[NQ], row4col[NQ], col4row[NT];
    __shared__ unsigned char SR[NT], SCm[NQ];
    __shared__ int s_i, s_sink;
    __shared__ double s_minVal;
    __shared__ int qv[NT];

    for (int idx = lane; idx < NT * NQ; idx += 64) {
        int r = idx / NQ, j = idx % NQ;
        cost[r][j] = (double)Cmat[((size_t)b * NQ + j) * NT + r];
    }
    for (int j = lane; j < NQ; j += 64) { v[j] = 0.0; row4col[j] = -1; }
    if (lane < NT) { u[lane] = 0.0; col4row[lane] = -1; }
    __syncthreads();

    for (int cur = 0; cur < NT; ++cur) {
        for (int j = lane; j < NQ; j += 64) { shortest[j] = INFINITY; path[j] = -1; SCm[j] = 0; }
        if (lane < NT) SR[lane] = 0;
        if (lane == 0) { s_i = cur; s_minVal = 0.0; s_sink = -1; }
        __syncthreads();

        while (true) {
            int i = s_i;
            double minVal = s_minVal;
            if (lane == 0) SR[i] = 1;
            double ui = u[i];
            double bestv = INFINITY;
            int bestj = NQ;
            for (int j = lane; j < NQ; j += 64) {
                if (!SCm[j]) {
                    double d = minVal + cost[i][j] - ui - v[j];
                    if (d < shortest[j]) { shortest[j] = d; path[j] = i; }
                    double sj = shortest[j];
                    if (sj < bestv || (sj == bestv && j < bestj)) { bestv = sj; bestj = j; }
                }
            }
            for (int o = 32; o; o >>= 1) {
                double ov = __shfl_xor(bestv, o);
                int oj = __shfl_xor(bestj, o);
                if (ov < bestv || (ov == bestv && oj < bestj)) { bestv = ov; bestj = oj; }
            }
            __syncthreads();
            if (lane == 0) {
                SCm[bestj] = 1;
                s_minVal = bestv;
                if (row4col[bestj] == -1) s_sink = bestj;
                else s_i = row4col[bestj];
            }
            __syncthreads();
            if (s_sink >= 0) break;
        }

        double minVal = s_minVal;
        int sink = s_sink;
        if (lane < NT) {
            if (lane == cur) u[lane] += minVal;
            else if (SR[lane]) u[lane] += minVal - shortest[col4row[lane]];
        }
        for (int j = lane; j < NQ; j += 64) {
            if (SCm[j]) v[j] -= minVal - shortest[j];
        }
        __syncthreads();
        if (lane == 0) {
            int j = sink;
            while (true) {
                int i = path[j];
                row4col[j] = i;
                int nj = col4row[i];
                col4row[i] = j;
                j = nj;
                if (i == cur) break;
            }
        }
        __syncthreads();
    }

    if (lane < NT) qv[lane] = col4row[lane];
    __syncthreads();
    if (lane < NT) {
        int my = qv[lane];
        int rank = 0;
#pragma unroll
        for (int t2 = 0; t2 < NT; ++t2) rank += (qv[t2] < my) ? 1 : 0;
        out[NB * NQ * NT + b * NT + rank] = (float)my;              // pred_idx
        out[NB * NQ * NT + NB * NT + b * NT + rank] = (float)lane;  // tgt_idx
    }
}

// ---------------------------------------------------------------------------
extern "C" void kernel_launch(void* const* d_in, const int* in_sizes, int n_in,
                              void* d_out, int out_size, void* d_ws, size_t ws_size,
                              hipStream_t stream) {
    const float* pred_logits = (const float*)d_in[0];   // [4,100,81]
    const float* pred_masks  = (const float*)d_in[1];   // [4,100,256,256]
    const float* tgt_masks   = (const float*)d_in[2];   // [4,20,512,512]
    const int*   tgt_labels  = (const int*)d_in[3];     // [4,20]
    float* out = (float*)d_out;

    char* ws = (char*)d_ws;
    float* A_part  = (float*)ws;                                      // SC*NB*NQR*21
    float* D_part  = A_part + (size_t)SC * NB * NQR * (NT + 1);
    float* Sp_part = D_part + (size_t)SC * NB * NQR * (NT + 1);       // SC*NB*NQ

    k_main<<<NB * SC, 256, 0, stream>>>(pred_masks, tgt_masks, A_part, D_part, Sp_part);
    k_assemble<<<NB * NQ, 256, 0, stream>>>(pred_logits, tgt_labels, A_part, D_part,
                                            Sp_part, out);
    k_lsa<<<NB, 64, 0, stream>>>(out, out);
}